// Round 8
// baseline (202.519 us; speedup 1.0000x reference)
//
#include <hip/hip_runtime.h>
#include <hip/hip_fp16.h>
#include <math.h>

typedef _Float16 half8  __attribute__((ext_vector_type(8)));
typedef _Float16 half2v __attribute__((ext_vector_type(2)));
typedef float   floatx4 __attribute__((ext_vector_type(4)));

#define ROWS   16384
#define DIM    128
#define KCODES 8192
#define NSPLIT 16
#define KSPLIT (KCODES / NSPLIT)   // 512 codes per split
#define NGROUP (KSPLIT / 16)       // 32 groups of 16 codes
#define MTILE  256                 // rows per block (4 waves x 64)
#define THR    0.3f                // decisive margin > 2*pass1 err (~0.2)

// ---------------- kernel 1: codebook fp16 + e2, LN-once -> xnh ----------------
__global__ __launch_bounds__(256) void prep_kernel(
    const float* __restrict__ cb, const float* __restrict__ x,
    _Float16* __restrict__ ehg, float* __restrict__ e2g,
    _Float16* __restrict__ xnh, float* __restrict__ out_loss)
{
  int tid = threadIdx.x;
  int L = tid & 63;
  int bx = blockIdx.x;
  if (bx == 0 && tid == 0) *out_loss = 0.f;   // gather accumulates atomically
  if (bx < KCODES / 4) {
    int row = bx * 4 + (tid >> 6);
    float2 v = ((const float2*)(cb + (size_t)row * DIM))[L];
    float s2 = v.x * v.x + v.y * v.y;
    #pragma unroll
    for (int m = 1; m < 64; m <<= 1) s2 += __shfl_xor(s2, m);
    if (L == 0) e2g[row] = -0.5f * s2;
    half2v hi = {(_Float16)v.x, (_Float16)v.y};
    ((half2v*)(ehg + (size_t)row * DIM))[L] = hi;
  } else {
    int row = (bx - KCODES / 4) * 4 + (tid >> 6);
    float2 xv = ((const float2*)(x + (size_t)row * DIM))[L];
    float s = xv.x + xv.y;
    #pragma unroll
    for (int m = 1; m < 64; m <<= 1) s += __shfl_xor(s, m);
    float mu = s * (1.0f / 128.0f);
    float dx = xv.x - mu, dy = xv.y - mu;
    float s2 = dx * dx + dy * dy;
    #pragma unroll
    for (int m = 1; m < 64; m <<= 1) s2 += __shfl_xor(s2, m);
    float rstd = 1.0f / sqrtf(s2 * (1.0f / 128.0f) + 1e-5f);
    half2v hv = {(_Float16)(dx * rstd), (_Float16)(dy * rstd)};
    ((half2v*)(xnh + (size_t)row * DIM))[L] = hv;
  }
}

// ---------------- kernel 2: argmin, B direct-from-L2 (no LDS staging) ----------------
// r6/r7 post-mortem: argmin 65us invariant to blocks/CU AND to MFMA work =>
// the global_load_lds -> LDS -> ds_read round-trip is the fixed cost. Key
// structural fact: the LDS buffer was wave-private and read ONCE -- zero
// reuse, pure latency buffer, for data (2MB fp16 codebook) that is L2-
// resident anyway (guide common-mistake #7). Fix: load B-fragments directly
// from global to registers (same 16B/lane the LDS path delivered -> numerics
// identical), manual 2x-unrolled ping-pong prefetch so the compiler emits
// counted vmcnt waits (register loads are the path it pipelines well).
// LDS = 2KB e2 table only.
// __launch_bounds__ CAUTION (r3): 2nd arg >2 caps VGPR at 64 -> spills.
__global__ __launch_bounds__(256, 2) void argmin_kernel(
    const _Float16* __restrict__ xnh, const _Float16* __restrict__ ehg,
    const float* __restrict__ e2g,
    float* __restrict__ b1p, int* __restrict__ i1p,
    float* __restrict__ b2p, int* __restrict__ i2p)
{
  __shared__ float e2l[KSPLIT];   // 2 KB, +256 bias baked in

  int tid = threadIdx.x;
  int w = tid >> 6, L = tid & 63, c = L & 15, q = L >> 4;
  int bx = blockIdx.x;
  int mt = bx & (ROWS / MTILE - 1);   // 0..63
  int ns = bx >> 6;                   // 0..15  (grid 1024)
  int rowbase = mt * MTILE + w * 64;
  int code0 = ns * KSPLIT;

  // A fragments from precomputed fp16 LN output
  half8 ah[4][4];
  #pragma unroll
  for (int g = 0; g < 4; ++g) {
    const _Float16* xr = xnh + (size_t)(rowbase + g * 16 + c) * DIM;
    #pragma unroll
    for (int ks = 0; ks < 4; ++ks)
      ah[g][ks] = *(const half8*)(xr + ks * 32 + q * 8);
  }

  // e2 -> LDS with +256 bias (acc stays positive for key packing)
  if (tid < KSPLIT / 4) {
    float4 v = ((const float4*)(e2g + code0))[tid];
    float4 o = {256.f + v.x, 256.f + v.y, 256.f + v.z, 256.f + v.w};
    ((float4*)e2l)[tid] = o;
  }
  __syncthreads();

  // per-lane B source: row (code0 + c), chunk (ks*4+q) -> halfs ks*32 + q*8
  const _Float16* bsrc = ehg + (size_t)(code0 + c) * DIM + q * 8;

  unsigned k1[4][4], k2[4][4];
  #pragma unroll
  for (int g = 0; g < 4; ++g)
    #pragma unroll
    for (int r = 0; r < 4; ++r) { k1[g][r] = 0u; k2[g][r] = 0u; }

  half8 bA[4], bB[4];
  #pragma unroll
  for (int ks = 0; ks < 4; ++ks) bA[ks] = *(const half8*)(bsrc + ks * 32);

  // one compute body: group g scored against fragments b[]
  #define COMPUTE(GIDX, BREG)                                                   \
    {                                                                           \
      float e2v = e2l[(GIDX) * 16 + c];                                         \
      unsigned gp = (unsigned)(GIDX);                                           \
      _Pragma("unroll")                                                         \
      for (int gg = 0; gg < 4; ++gg) {                                          \
        floatx4 acc = {e2v, e2v, e2v, e2v};                                     \
        _Pragma("unroll")                                                       \
        for (int ks = 0; ks < 4; ++ks)                                          \
          acc = __builtin_amdgcn_mfma_f32_16x16x32_f16(ah[gg][ks], BREG[ks],    \
                                                       acc, 0, 0, 0);           \
        _Pragma("unroll")                                                       \
        for (int r = 0; r < 4; ++r) {                                           \
          unsigned kk = (__float_as_uint(acc[r]) & 0xFFFFFFC0u) | gp;           \
          unsigned tt = kk < k1[gg][r] ? kk : k1[gg][r];                        \
          k1[gg][r] = kk > k1[gg][r] ? kk : k1[gg][r];                          \
          k2[gg][r] = tt > k2[gg][r] ? tt : k2[gg][r];                          \
        }                                                                       \
      }                                                                         \
    }

  for (int g = 0; g < NGROUP; g += 2) {
    // prefetch group g+1 while computing g
    const _Float16* p1 = bsrc + (size_t)(g + 1) * 16 * DIM;
    #pragma unroll
    for (int ks = 0; ks < 4; ++ks) bB[ks] = *(const half8*)(p1 + ks * 32);
    COMPUTE(g, bA);
    // prefetch group g+2 while computing g+1
    if (g + 2 < NGROUP) {
      const _Float16* p2 = bsrc + (size_t)(g + 2) * 16 * DIM;
      #pragma unroll
      for (int ks = 0; ks < 4; ++ks) bA[ks] = *(const half8*)(p2 + ks * 32);
    }
    COMPUTE(g + 1, bB);
  }
  #undef COMPUTE

  // epilogue: unpack -> merge top-2 across the 16 c-lanes of each quad
  #pragma unroll
  for (int gg = 0; gg < 4; ++gg)
    #pragma unroll
    for (int r = 0; r < 4; ++r) {
      float s1 = __uint_as_float(k1[gg][r] & 0xFFFFFFC0u) - 256.f;
      float s2 = __uint_as_float(k2[gg][r] & 0xFFFFFFC0u) - 256.f;
      int   j1 = code0 + (int)(k1[gg][r] & 63u) * 16 + c;
      int   j2 = code0 + (int)(k2[gg][r] & 63u) * 16 + c;
      #pragma unroll
      for (int m = 1; m < 16; m <<= 1) {
        float o1 = __shfl_xor(s1, m); int oj1 = __shfl_xor(j1, m);
        float o2 = __shfl_xor(s2, m); int oj2 = __shfl_xor(j2, m);
        if (o1 > s1) {
          bool t = (s1 >= o2);
          s2 = t ? s1 : o2;  j2 = t ? j1 : oj2;
          s1 = o1; j1 = oj1;
        } else {
          bool t = (o1 >= s2);
          s2 = t ? o1 : s2;  j2 = t ? oj1 : j2;
        }
      }
      if (c == 0) {
        int row = rowbase + gg * 16 + q * 4 + r;
        b1p[(size_t)row * NSPLIT + ns] = s1; i1p[(size_t)row * NSPLIT + ns] = j1;
        b2p[(size_t)row * NSPLIT + ns] = s2; i2p[(size_t)row * NSPLIT + ns] = j2;
      }
    }
}

// ---------------- kernel 3: fast-path rescore + gather + fused loss ----------------
// 32 candidates/row (16 splits x top-2). Pass-1 scores exact to E~0.1; if the
// max beats every other candidate by THR > 2E the winner is provable without
// any exact dot (most rows). Ambiguous rows: exact fp32 rescore of survivors.
__global__ __launch_bounds__(256) void gather_loss_kernel(
    const float* __restrict__ x, const float* __restrict__ cb,
    const float* __restrict__ e2g,
    const float* __restrict__ b1p, const int* __restrict__ i1p,
    const float* __restrict__ b2p, const int* __restrict__ i2p,
    float* __restrict__ out_q, float* __restrict__ out_ind,
    float* __restrict__ out_loss)
{
  __shared__ float lsum[4];
  int tid = threadIdx.x;
  int L = tid & 63;
  int w = tid >> 6;
  int row = blockIdx.x * 4 + w;

  int k  = L & 31;
  int qd = L >> 5;

  // lanes 0..15: split L top-1; lanes 16..31: split (L-16) top-2
  int ci = 0; float cv = -3.4e38f;
  if (L < 16)      { ci = i1p[(size_t)row * NSPLIT + L];        cv = b1p[(size_t)row * NSPLIT + L]; }
  else if (L < 32) { ci = i2p[(size_t)row * NSPLIT + (L - 16)]; cv = b2p[(size_t)row * NSPLIT + (L - 16)]; }
  int   idxk = __shfl(ci, k);
  float tvk  = __shfl(cv, k);

  float tmax = tvk;
  #pragma unroll
  for (int m = 1; m < 32; m <<= 1) tmax = fmaxf(tmax, __shfl_xor(tmax, m));
  bool keep = tvk >= tmax - THR;
  unsigned long long mb = __ballot(keep);   // 2 set bits per surviving candidate

  // LayerNorm stats (exact fp32) -- needed for loss regardless of path
  float2 xv = ((const float2*)(x + (size_t)row * DIM))[L];
  float s = xv.x + xv.y;
  #pragma unroll
  for (int m = 1; m < 64; m <<= 1) s += __shfl_xor(s, m);
  float mu = s * (1.0f / 128.0f);
  float dx = xv.x - mu, dy = xv.y - mu;
  float s2 = dx * dx + dy * dy;
  #pragma unroll
  for (int m = 1; m < 64; m <<= 1) s2 += __shfl_xor(s2, m);
  float rstd = 1.0f / sqrtf(s2 * (1.0f / 128.0f) + 1e-5f);

  int bi;
  if (__popcll(mb) == 2) {
    // decisive: the unique survivor is the exact winner
    int lsel = (int)__ffsll(mb) - 1;
    bi = __shfl(idxk, lsel);
  } else {
    // exact dot over this lane's 64-dim half of candidate idxk (survivors)
    float p = 0.f;
    if (keep) {
      const float4* xr4 = (const float4*)(x  + (size_t)row  * DIM);
      const float4* er4 = (const float4*)(cb + (size_t)idxk * DIM);
      #pragma unroll
      for (int j = 0; j < 16; ++j) {
        float4 a = xr4[qd * 16 + j];
        float4 e = er4[qd * 16 + j];
        p += (a.x - mu) * e.x + (a.y - mu) * e.y + (a.z - mu) * e.z + (a.w - mu) * e.w;
      }
      p *= rstd;
    }
    p += __shfl_xor(p, 32);                    // both halves share 'keep'
    float t = keep ? p + e2g[idxk] : -3.4e38f; // e2g = -0.5*||e||^2 exact
    bi = idxk;
    #pragma unroll
    for (int m = 1; m < 32; m <<= 1) {
      float ot = __shfl_xor(t, m);
      int   oi = __shfl_xor(bi, m);
      if (ot > t || (ot == t && oi < bi)) { t = ot; bi = oi; }
    }
  }

  float2 qv = ((const float2*)(cb + (size_t)bi * DIM))[L];
  ((float2*)out_q)[(size_t)row * 64 + L] = qv;
  float xn0 = dx * rstd, xn1 = dy * rstd;
  float e0 = qv.x - xn0, e1 = qv.y - xn1;
  float le = e0 * e0 + e1 * e1;
  #pragma unroll
  for (int m = 1; m < 64; m <<= 1) le += __shfl_xor(le, m);
  if (L == 0) {
    lsum[w] = le;
    out_ind[row] = (float)bi;
  }
  __syncthreads();
  if (tid == 0)
    atomicAdd(out_loss, (lsum[0] + lsum[1] + lsum[2] + lsum[3]) * (1.0f / ((float)ROWS * DIM)));
}

extern "C" void kernel_launch(void* const* d_in, const int* in_sizes, int n_in,
                              void* d_out, int out_size, void* d_ws, size_t ws_size,
                              hipStream_t stream)
{
  const float* x  = (const float*)d_in[0];   // [4,4096,128] fp32
  const float* cb = (const float*)d_in[1];   // [8192,128]  fp32

  char* ws = (char*)d_ws;
  _Float16* ehg = (_Float16*)(ws + 0);        // 2 MB
  float*    e2g = (float*)   (ws + 2097152);  // 32 KB
  float*    b1p = (float*)   (ws + 2129920);  // 1 MB
  int*      i1p = (int*)     (ws + 3178496);  // 1 MB
  float*    b2p = (float*)   (ws + 4227072);  // 1 MB
  int*      i2p = (int*)     (ws + 5275648);  // 1 MB

  float* out_q    = (float*)d_out;                   // 16384*128
  float* out_ind  = out_q + (size_t)ROWS * DIM;      // 16384 (as float)
  float* out_loss = out_ind + ROWS;                  // 1

  // xnh (fp16 LN output, 4 MB) lives in the out_q region: written by prep,
  // read by argmin; out_q is only written afterwards by gather.
  _Float16* xnh = (_Float16*)out_q;

  prep_kernel<<<KCODES / 4 + ROWS / 4, 256, 0, stream>>>(cb, x, ehg, e2g, xnh, out_loss);
  argmin_kernel<<<(ROWS / MTILE) * NSPLIT, 256, 0, stream>>>(xnh, ehg, e2g, b1p, i1p, b2p, i2p);
  gather_loss_kernel<<<ROWS / 4, 256, 0, stream>>>(x, cb, e2g, b1p, i1p, b2p, i2p, out_q, out_ind, out_loss);
}